// Round 20
// baseline (100.270 us; speedup 1.0000x reference)
//
#include <hip/hip_runtime.h>
#include <hip/hip_bf16.h>
#include <math.h>

#define BB 16
#define NN 16384
#define DD 256
#define KK 32

typedef short bf16x8 __attribute__((ext_vector_type(8)));
typedef float f32x4 __attribute__((ext_vector_type(4)));

__device__ inline unsigned pk2(float lo, float hi) {
    __hip_bfloat162 h = __float22bfloat162_rn(make_float2(lo, hi));
    union { __hip_bfloat162 h; unsigned u; } v; v.h = h;
    return v.u;
}
__device__ inline bf16x8 u4bf(uint4 q) {
    union { uint4 u; bf16x8 v; } c; c.u = q; return c.v;
}

// compile-time float4 component select
#define CAE(vv, e) ((e) == 0 ? (vv).x : (e) == 1 ? (vv).y : (e) == 2 ? (vv).z : (vv).w)

// r11's d-half wave split, re-tried under r19 conditions (single-round
// residency, fence-free): wave w: rg = w>>1 owns rows rg*16..+15 of each
// 32-row sub; dh = w&1 owns d-half. acc = 64 VGPRs -> fits 2 waves/SIMD at
// bounds(256,2); TLP covers the 1.3us/sub serial chain r19 left exposed.
// Grid 512 = 2 blocks/CU, all-resident, 512 rows/block (16 subs).
// NO in-loop fences (r18: -4.5us; same-wave DS in-order, xt wave-private).
__launch_bounds__(256, 2)
__global__ void netvlad_k1(const float* __restrict__ x,
                           const float* __restrict__ W,
                           const float* __restrict__ bias,
                           float* __restrict__ vpart,
                           float* __restrict__ apart) {
    __shared__ __align__(16) char lds[33280];
    // [0,16384):     Wl bf16, byte = k*512 + (dbyte ^ ((k&7)<<4))
    // [16384,32768): xt per-wave 4KB: d_local*32 + (nbyte ^ (((d_local>>3)&1)<<4))
    // epilogue: vbuf f32 [32][260] at byte 0 (33280 B)

    const int t   = threadIdx.x;
    const int l   = t & 63;
    const int w   = t >> 6;
    const int rg  = w >> 1;            // row-group: rows rg*16..+15 of each sub
    const int dh  = w & 1;             // d-half: [dh*128, dh*128+128)
    const int l15 = l & 15;
    const int lg4 = l >> 4;
    const int rh  = l >> 5;            // ca row-half (0..1)
    const int cl  = l & 31;            // ca col slot
    const int bid = blockIdx.x;
    const int b   = bid >> 5;          // batch (32 blocks per batch)
    const int blk = bid & 31;          // 512-row chunk

    // ---- stage Wl (bf16, swizzled) once ----
    for (int i = 0; i < 8; i++) {
        int f = i * 256 + t;           // float4 index in [0,2048)
        int k = f >> 6, c4 = f & 63;
        float4 wv = ((const float4*)W)[f];
        int byte = k * 512 + ((c4 * 8) ^ ((k & 7) << 4));
        *(uint2*)(lds + byte) = make_uint2(pk2(wv.x, wv.y), pk2(wv.z, wv.w));
    }
    const float cb0 = bias[l15];
    const float cb1 = bias[16 + l15];
    __syncthreads();                   // once; Wl read-only afterwards

    char* xtw = lds + 16384 + w * 4096;

    f32x4 acc0[8], acc1[8];
#pragma unroll
    for (int i = 0; i < 8; i++) { acc0[i] = (f32x4){0,0,0,0}; acc1[i] = (f32x4){0,0,0,0}; }
    float asr0 = 0.f, asr1 = 0.f;

    const float* xbase = x + ((size_t)b * NN + (size_t)blk * 512) * DD;

    // prologue: prefetch sub-0 row-slices (full own row; pair-duplicate merges in L2)
    float4 pf[16];
    {
        const float* xr = xbase + (size_t)(rg * 16 + l15) * DD + lg4 * 8;
#pragma unroll
        for (int ks = 0; ks < 8; ks++) {
            pf[2 * ks]     = *(const float4*)(xr + ks * 32);
            pf[2 * ks + 1] = *(const float4*)(xr + ks * 32 + 4);
        }
    }

    uint4 af0 = make_uint4(0, 0, 0, 0), af1 = make_uint4(0, 0, 0, 0);

#pragma unroll 1
    for (int s = 0; s < 16; s++) {
        const float* xsub = xbase + ((size_t)s * 32 + (size_t)rg * 16) * DD;

        // A: ca col-loads — 8 rows (rh half) x 4 cols of own d-half (L2-hot)
        float4 ca[8];
#pragma unroll
        for (int i = 0; i < 8; i++)
            ca[i] = *(const float4*)(xsub + (size_t)(rh * 8 + i) * DD + dh * 128 + cl * 4);

        // B: deferred aggregation for sub s-1 (covers ca latency; same-wave
        // DS in-order -> xt from prev C/D visible without fences)
        if (s > 0) {
#pragma unroll
            for (int dt = 0; dt < 8; dt++) {
                int dl = dt * 16 + l15;
                unsigned sw = ((unsigned)(dl >> 3) & 1u) << 4;
                uint2 blv = *(const uint2*)(xtw + dl * 32 + ((lg4 * 8) ^ sw));
                bf16x8 bv = u4bf(make_uint4(blv.x, blv.y, 0, 0));
                acc0[dt] = __builtin_amdgcn_mfma_f32_16x16x32_bf16(u4bf(af0), bv, acc0[dt], 0, 0, 0);
                acc1[dt] = __builtin_amdgcn_mfma_f32_16x16x32_bf16(u4bf(af1), bv, acc1[dt], 0, 0, 0);
            }
        }

        // C/D: stage wave-private x^T quarter-tile (128 d x 16 n bf16)
#pragma unroll
        for (int e = 0; e < 4; e++) {
            int dl = cl * 4 + e;
            unsigned sw = ((unsigned)(dl >> 3) & 1u) << 4;
            uint4 q;
            q.x = pk2(CAE(ca[0], e), CAE(ca[1], e));
            q.y = pk2(CAE(ca[2], e), CAE(ca[3], e));
            q.z = pk2(CAE(ca[4], e), CAE(ca[5], e));
            q.w = pk2(CAE(ca[6], e), CAE(ca[7], e));
            *(uint4*)(xtw + dl * 32 + (((unsigned)(rh * 16)) ^ sw)) = q;
        }

        // E: logits mfma(A = x row-frags from pf, B = W^T from Wl)
        f32x4 c0 = (f32x4){cb0, cb0, cb0, cb0};
        f32x4 c1 = (f32x4){cb1, cb1, cb1, cb1};
        {
            const unsigned swk = ((unsigned)(l15 & 7)) << 4;
#pragma unroll
            for (int ks = 0; ks < 8; ks++) {
                uint4 xq;
                xq.x = pk2(pf[2 * ks].x,     pf[2 * ks].y);
                xq.y = pk2(pf[2 * ks].z,     pf[2 * ks].w);
                xq.z = pk2(pf[2 * ks + 1].x, pf[2 * ks + 1].y);
                xq.w = pk2(pf[2 * ks + 1].z, pf[2 * ks + 1].w);
                bf16x8 ax = u4bf(xq);
                bf16x8 w0 = *(const bf16x8*)(lds + l15 * 512        + (((unsigned)(ks * 64 + lg4 * 16)) ^ swk));
                bf16x8 w1 = *(const bf16x8*)(lds + (16 + l15) * 512 + (((unsigned)(ks * 64 + lg4 * 16)) ^ swk));
                c0 = __builtin_amdgcn_mfma_f32_16x16x32_bf16(ax, w0, c0, 0, 0, 0);
                c1 = __builtin_amdgcn_mfma_f32_16x16x32_bf16(ax, w1, c1, 0, 0, 0);
            }
        }

        // F: issue next sub's HBM row-slice prefetch
        if (s < 15) {
            const float* xr = xbase + ((size_t)(s + 1) * 32 + (size_t)(rg * 16 + l15)) * DD + lg4 * 8;
#pragma unroll
            for (int ks = 0; ks < 8; ks++) {
                pf[2 * ks]     = *(const float4*)(xr + ks * 32);
                pf[2 * ks + 1] = *(const float4*)(xr + ks * 32 + 4);
            }
        }

        // G: softmax over k=32, fully in-register
        float a0v[4], a1v[4];
#pragma unroll
        for (int r = 0; r < 4; r++) {
            float m = fmaxf(c0[r], c1[r]);
            m = fmaxf(m, __shfl_xor(m, 1));
            m = fmaxf(m, __shfl_xor(m, 2));
            m = fmaxf(m, __shfl_xor(m, 4));
            m = fmaxf(m, __shfl_xor(m, 8));
            float p0 = __expf(c0[r] - m), p1 = __expf(c1[r] - m);
            float ss = p0 + p1;
            ss += __shfl_xor(ss, 1);
            ss += __shfl_xor(ss, 2);
            ss += __shfl_xor(ss, 4);
            ss += __shfl_xor(ss, 8);
            float inv = 1.0f / ss;
            a0v[r] = p0 * inv; a1v[r] = p1 * inv;
        }
        asr0 += a0v[0] + a0v[1] + a0v[2] + a0v[3];
        asr1 += a1v[0] + a1v[1] + a1v[2] + a1v[3];
        af0 = make_uint4(pk2(a0v[0], a0v[1]), pk2(a0v[2], a0v[3]), 0, 0);
        af1 = make_uint4(pk2(a1v[0], a1v[1]), pk2(a1v[2], a1v[3]), 0, 0);
    }

    // tail aggregation for sub 15
#pragma unroll
    for (int dt = 0; dt < 8; dt++) {
        int dl = dt * 16 + l15;
        unsigned sw = ((unsigned)(dl >> 3) & 1u) << 4;
        uint2 blv = *(const uint2*)(xtw + dl * 32 + ((lg4 * 8) ^ sw));
        bf16x8 bv = u4bf(make_uint4(blv.x, blv.y, 0, 0));
        acc0[dt] = __builtin_amdgcn_mfma_f32_16x16x32_bf16(u4bf(af0), bv, acc0[dt], 0, 0, 0);
        acc1[dt] = __builtin_amdgcn_mfma_f32_16x16x32_bf16(u4bf(af1), bv, acc1[dt], 0, 0, 0);
    }

    // ---- asum: reduce over lg4 groups; dh==0 wave of each pair stores ----
    asr0 += __shfl_xor(asr0, 16);  asr0 += __shfl_xor(asr0, 32);
    asr1 += __shfl_xor(asr1, 16);  asr1 += __shfl_xor(asr1, 32);
    if (dh == 0 && l < 16) {
        float* ap = apart + ((size_t)bid * 2 + rg) * KK;
        ap[l15]      = asr0;
        ap[16 + l15] = asr1;
    }

    // ---- epilogue: cross-pair v reduce via LDS (Wl/xt dead) ----
    __syncthreads();
    float* vb = (float*)lds;           // [32][260] f32
    if (rg == 0) {
#pragma unroll
        for (int dt = 0; dt < 8; dt++) {
            int d = dh * 128 + dt * 16 + l15;
#pragma unroll
            for (int r = 0; r < 4; r++) {
                int k0 = lg4 * 4 + r;
                vb[k0 * 260 + d]        = acc0[dt][r];
                vb[(16 + k0) * 260 + d] = acc1[dt][r];
            }
        }
    }
    __syncthreads();
    if (rg == 1) {
#pragma unroll
        for (int dt = 0; dt < 8; dt++) {
            int d = dh * 128 + dt * 16 + l15;
#pragma unroll
            for (int r = 0; r < 4; r++) {
                int k0 = lg4 * 4 + r;
                vb[k0 * 260 + d]        += acc0[dt][r];
                vb[(16 + k0) * 260 + d] += acc1[dt][r];
            }
        }
    }
    __syncthreads();
    float* vp = vpart + (size_t)bid * KK * DD;
#pragma unroll
    for (int i = 0; i < 8; i++) {
        int f = i * 256 + t;
        int k = f >> 6, c4 = f & 63;
        f32x4 v4 = *(const f32x4*)&vb[k * 260 + c4 * 4];
        *(f32x4*)&vp[(size_t)k * DD + c4 * 4] = v4;
    }
}

// kC: reduce 32 v-partials + 64 asum-partials, subtract a_sum*k_mean, normalize.
__global__ void netvlad_kC(const float* __restrict__ vpart,
                           const float* __restrict__ apart,
                           const float* __restrict__ kmean,
                           float* __restrict__ out) {
    const int bi = blockIdx.x / KK;
    const int k  = blockIdx.x % KK;
    const int t  = threadIdx.x;   // d

    float v = 0.0f;
    for (int j = 0; j < 32; j++)
        v += vpart[(((size_t)bi * 32 + j) * KK + k) * DD + t];

    float asum = 0.0f;
    for (int j = 0; j < 64; j++)
        asum += apart[((size_t)bi * 64 + j) * KK + k];

    v -= asum * kmean[(size_t)k * DD + t];

    float sq = v * v;
    sq += __shfl_xor(sq, 1);  sq += __shfl_xor(sq, 2);  sq += __shfl_xor(sq, 4);
    sq += __shfl_xor(sq, 8);  sq += __shfl_xor(sq, 16); sq += __shfl_xor(sq, 32);
    __shared__ float red[4];
    if ((t & 63) == 0) red[t >> 6] = sq;
    __syncthreads();
    float tot = red[0] + red[1] + red[2] + red[3];

    const float EPS = 1e-12f;
    float invn = 1.0f / fmaxf(sqrtf(tot), EPS);
    const float invK = 0.1767766952966369f;  // 1/sqrt(32): global norm after intra-norm
    out[((size_t)bi * KK + k) * DD + t] = v * invn * invK;
}

extern "C" void kernel_launch(void* const* d_in, const int* in_sizes, int n_in,
                              void* d_out, int out_size, void* d_ws, size_t ws_size,
                              hipStream_t stream) {
    const float* x     = (const float*)d_in[0];
    const float* W     = (const float*)d_in[1];
    const float* bias  = (const float*)d_in[2];
    const float* kmean = (const float*)d_in[3];
    float* out = (float*)d_out;

    // ws carve: vpart (512*32*256 f32 = 16.8MB) | apart (1024*32 f32 = 128KB)
    float* vpart = (float*)d_ws;
    float* apart = vpart + (size_t)512 * KK * DD;

    hipLaunchKernelGGL(netvlad_k1, dim3(512), dim3(256), 0, stream,
                       x, W, bias, vpart, apart);
    hipLaunchKernelGGL(netvlad_kC, dim3(BB * KK), dim3(256), 0, stream,
                       vpart, apart, kmean, out);
}

// Round 21
// 67.835 us; speedup vs baseline: 1.4781x; 1.4781x over previous
//
#include <hip/hip_runtime.h>
#include <hip/hip_bf16.h>
#include <math.h>

#define BB 16
#define NN 16384
#define DD 256
#define KK 32

typedef short bf16x8 __attribute__((ext_vector_type(8)));
typedef float f32x4 __attribute__((ext_vector_type(4)));

__device__ inline unsigned pk2(float lo, float hi) {
    __hip_bfloat162 h = __float22bfloat162_rn(make_float2(lo, hi));
    union { __hip_bfloat162 h; unsigned u; } v; v.h = h;
    return v.u;
}
__device__ inline bf16x8 u4bf(uint4 q) {
    union { uint4 u; bf16x8 v; } c; c.u = q; return c.v;
}

// compile-time float4 component select
#define CAE(vv, e) ((e) == 0 ? (vv).x : (e) == 1 ? (vv).y : (e) == 2 ? (vv).z : (vv).w)

// FINAL STRUCTURE (r19, 67.9us): fence-free, 256 blocks (1 per CU, single
// residency round), 1024 rows/block (16 subs), 4 independent waves each owning
// 16 rows end-to-end; bounds(256,1) -> 512 regs/wave, zero spill.
// r20's d-half split (2 blocks/CU) regressed to 100us: duplicated logits VALU +
// broken per-CU streaming locality. Reverted per pre-committed rule.
__launch_bounds__(256, 1)
__global__ void netvlad_k1(const float* __restrict__ x,
                           const float* __restrict__ W,
                           const float* __restrict__ bias,
                           float* __restrict__ vpart,
                           float* __restrict__ apart) {
    __shared__ __align__(16) char lds[49152];
    // [0,16384): Wl bf16, byte = k*512 + (dbyte ^ ((k&7)<<4))
    // [16384,49152): xt per-wave 8KB: d*32 + (nbyte ^ (((d>>3)&1)<<4))
    // epilogue: vbuf f32 [32][260] at byte 0

    const int t   = threadIdx.x;
    const int l   = t & 63;
    const int w   = t >> 6;
    const int l15 = l & 15;
    const int lg4 = l >> 4;
    const int bid = blockIdx.x;
    const int b   = bid >> 4;            // batch (16 blocks per batch)
    const int blk = bid & 15;            // 1024-row chunk

    // ---- stage Wl (bf16, swizzled) once ----
    for (int i = 0; i < 8; i++) {
        int f = i * 256 + t;             // float4 index in [0,2048)
        int k = f >> 6, c4 = f & 63;
        float4 wv = ((const float4*)W)[f];
        int byte = k * 512 + ((c4 * 8) ^ ((k & 7) << 4));
        *(uint2*)(lds + byte) = make_uint2(pk2(wv.x, wv.y), pk2(wv.z, wv.w));
    }
    const float cb0 = bias[l15];
    const float cb1 = bias[16 + l15];
    __syncthreads();                     // once; Wl read-only afterwards

    char* xtw = lds + 16384 + w * 8192;

    f32x4 acc0[16], acc1[16];
#pragma unroll
    for (int i = 0; i < 16; i++) { acc0[i] = (f32x4){0,0,0,0}; acc1[i] = (f32x4){0,0,0,0}; }
    float asr0 = 0.f, asr1 = 0.f;

    const float* xbase = x + ((size_t)b * NN + (size_t)blk * 1024) * DD;

    // prologue: prefetch sub-0 row-slices: pf[2ks+h] = x[w*16+l15][ks*32+lg4*8+h*4..]
    float4 pf[16];
    {
        const float* xr = xbase + (size_t)(w * 16 + l15) * DD + lg4 * 8;
#pragma unroll
        for (int ks = 0; ks < 8; ks++) {
            pf[2 * ks]     = *(const float4*)(xr + ks * 32);
            pf[2 * ks + 1] = *(const float4*)(xr + ks * 32 + 4);
        }
    }

    uint4 af0 = make_uint4(0, 0, 0, 0), af1 = make_uint4(0, 0, 0, 0);

#pragma unroll 1
    for (int s = 0; s < 16; s++) {
        const float* xsub = xbase + ((size_t)s * 64 + (size_t)w * 16) * DD;

        // A: issue ca col-loads rows 0-7 (L2/L3-hot: pf stream fetched these lines)
        float4 ca[8];
#pragma unroll
        for (int i = 0; i < 8; i++)
            ca[i] = *(const float4*)(xsub + (size_t)i * DD + l * 4);

        // B: deferred aggregation for sub s-1 (covers ca latency).
        // Same-wave DS in-order: xt writes from C/D of sub s-1 are visible.
        if (s > 0) {
#pragma unroll
            for (int dt = 0; dt < 16; dt++) {
                int d = dt * 16 + l15;
                unsigned sw = ((unsigned)(d >> 3) & 1u) << 4;
                uint2 bl = *(const uint2*)(xtw + d * 32 + ((lg4 * 8) ^ sw));
                bf16x8 bv = u4bf(make_uint4(bl.x, bl.y, 0, 0));
                acc0[dt] = __builtin_amdgcn_mfma_f32_16x16x32_bf16(u4bf(af0), bv, acc0[dt], 0, 0, 0);
                acc1[dt] = __builtin_amdgcn_mfma_f32_16x16x32_bf16(u4bf(af1), bv, acc1[dt], 0, 0, 0);
            }
        }

        // C/D: stage wave-private x^T tile (two 8-row halves, register transpose)
#pragma unroll
        for (int half = 0; half < 2; half++) {
            if (half == 1) {
#pragma unroll
                for (int i = 0; i < 8; i++)
                    ca[i] = *(const float4*)(xsub + (size_t)(8 + i) * DD + l * 4);
            }
#pragma unroll
            for (int e = 0; e < 4; e++) {
                int d = 4 * l + e;
                unsigned sw = ((unsigned)(d >> 3) & 1u) << 4;
                uint4 q;
                q.x = pk2(CAE(ca[0], e), CAE(ca[1], e));
                q.y = pk2(CAE(ca[2], e), CAE(ca[3], e));
                q.z = pk2(CAE(ca[4], e), CAE(ca[5], e));
                q.w = pk2(CAE(ca[6], e), CAE(ca[7], e));
                *(uint4*)(xtw + d * 32 + (((unsigned)(half * 16)) ^ sw)) = q;
            }
        }

        // E: logits mfma(A = x row-frags from pf, B = W^T from Wl)
        f32x4 c0 = (f32x4){cb0, cb0, cb0, cb0};
        f32x4 c1 = (f32x4){cb1, cb1, cb1, cb1};
        {
            const unsigned swk = ((unsigned)(l15 & 7)) << 4;
#pragma unroll
            for (int ks = 0; ks < 8; ks++) {
                uint4 xq;
                xq.x = pk2(pf[2 * ks].x,     pf[2 * ks].y);
                xq.y = pk2(pf[2 * ks].z,     pf[2 * ks].w);
                xq.z = pk2(pf[2 * ks + 1].x, pf[2 * ks + 1].y);
                xq.w = pk2(pf[2 * ks + 1].z, pf[2 * ks + 1].w);
                bf16x8 ax = u4bf(xq);
                bf16x8 w0 = *(const bf16x8*)(lds + l15 * 512        + (((unsigned)(ks * 64 + lg4 * 16)) ^ swk));
                bf16x8 w1 = *(const bf16x8*)(lds + (16 + l15) * 512 + (((unsigned)(ks * 64 + lg4 * 16)) ^ swk));
                c0 = __builtin_amdgcn_mfma_f32_16x16x32_bf16(ax, w0, c0, 0, 0, 0);
                c1 = __builtin_amdgcn_mfma_f32_16x16x32_bf16(ax, w1, c1, 0, 0, 0);
            }
        }

        // F: issue next sub's HBM row-slice prefetch (in flight across softmax+agg)
        if (s < 15) {
            const float* xr = xbase + ((size_t)(s + 1) * 64 + (size_t)(w * 16 + l15)) * DD + lg4 * 8;
#pragma unroll
            for (int ks = 0; ks < 8; ks++) {
                pf[2 * ks]     = *(const float4*)(xr + ks * 32);
                pf[2 * ks + 1] = *(const float4*)(xr + ks * 32 + 4);
            }
        }

        // G: softmax over k=32 (16 lanes x 2 tiles), fully in-register
        float a0v[4], a1v[4];
#pragma unroll
        for (int r = 0; r < 4; r++) {
            float m = fmaxf(c0[r], c1[r]);
            m = fmaxf(m, __shfl_xor(m, 1));
            m = fmaxf(m, __shfl_xor(m, 2));
            m = fmaxf(m, __shfl_xor(m, 4));
            m = fmaxf(m, __shfl_xor(m, 8));
            float p0 = __expf(c0[r] - m), p1 = __expf(c1[r] - m);
            float ss = p0 + p1;
            ss += __shfl_xor(ss, 1);
            ss += __shfl_xor(ss, 2);
            ss += __shfl_xor(ss, 4);
            ss += __shfl_xor(ss, 8);
            float inv = 1.0f / ss;
            a0v[r] = p0 * inv; a1v[r] = p1 * inv;
        }
        asr0 += a0v[0] + a0v[1] + a0v[2] + a0v[3];
        asr1 += a1v[0] + a1v[1] + a1v[2] + a1v[3];
        af0 = make_uint4(pk2(a0v[0], a0v[1]), pk2(a0v[2], a0v[3]), 0, 0);
        af1 = make_uint4(pk2(a1v[0], a1v[1]), pk2(a1v[2], a1v[3]), 0, 0);
    }

    // tail aggregation for sub 15 (same-wave DS in-order guarantees xt visible)
#pragma unroll
    for (int dt = 0; dt < 16; dt++) {
        int d = dt * 16 + l15;
        unsigned sw = ((unsigned)(d >> 3) & 1u) << 4;
        uint2 bl = *(const uint2*)(xtw + d * 32 + ((lg4 * 8) ^ sw));
        bf16x8 bv = u4bf(make_uint4(bl.x, bl.y, 0, 0));
        acc0[dt] = __builtin_amdgcn_mfma_f32_16x16x32_bf16(u4bf(af0), bv, acc0[dt], 0, 0, 0);
        acc1[dt] = __builtin_amdgcn_mfma_f32_16x16x32_bf16(u4bf(af1), bv, acc1[dt], 0, 0, 0);
    }

    // ---- asum: reduce over lg4 groups; per-wave global partials ----
    asr0 += __shfl_xor(asr0, 16);  asr0 += __shfl_xor(asr0, 32);
    asr1 += __shfl_xor(asr1, 16);  asr1 += __shfl_xor(asr1, 32);
    if (l < 16) {
        float* ap = apart + ((size_t)bid * 4 + w) * KK;
        ap[l15]      = asr0;
        ap[16 + l15] = asr1;
    }

    // ---- epilogue: cross-wave v reduce via LDS (Wl/xt dead) ----
    __syncthreads();
    float* vb = (float*)lds;             // [32][260] f32
    if ((w & 1) == 0) {                  // (kept from r19: no-op branch)
    }
    if (w == 0) {
#pragma unroll
        for (int dt = 0; dt < 16; dt++) {
            int d = dt * 16 + l15;
#pragma unroll
            for (int r = 0; r < 4; r++) {
                int k0 = lg4 * 4 + r;
                vb[k0 * 260 + d]        = acc0[dt][r];
                vb[(16 + k0) * 260 + d] = acc1[dt][r];
            }
        }
    }
    __syncthreads();
    if (w == 1 || w == 2) {
        if (w == 1) {
#pragma unroll
            for (int dt = 0; dt < 16; dt++) {
                int d = dt * 16 + l15;
#pragma unroll
                for (int r = 0; r < 4; r++) {
                    int k0 = lg4 * 4 + r;
                    vb[k0 * 260 + d]        += acc0[dt][r];
                    vb[(16 + k0) * 260 + d] += acc1[dt][r];
                }
            }
        }
    }
    __syncthreads();
    if (w == 2) {
#pragma unroll
        for (int dt = 0; dt < 16; dt++) {
            int d = dt * 16 + l15;
#pragma unroll
            for (int r = 0; r < 4; r++) {
                int k0 = lg4 * 4 + r;
                vb[k0 * 260 + d]        += acc0[dt][r];
                vb[(16 + k0) * 260 + d] += acc1[dt][r];
            }
        }
    }
    __syncthreads();
    if (w == 3) {
#pragma unroll
        for (int dt = 0; dt < 16; dt++) {
            int d = dt * 16 + l15;
#pragma unroll
            for (int r = 0; r < 4; r++) {
                int k0 = lg4 * 4 + r;
                vb[k0 * 260 + d]        += acc0[dt][r];
                vb[(16 + k0) * 260 + d] += acc1[dt][r];
            }
        }
    }
    __syncthreads();
    float* vp = vpart + (size_t)bid * KK * DD;
#pragma unroll
    for (int i = 0; i < 8; i++) {
        int f = i * 256 + t;
        int k = f >> 6, c4 = f & 63;
        f32x4 v4 = *(const f32x4*)&vb[k * 260 + c4 * 4];
        *(f32x4*)&vp[(size_t)k * DD + c4 * 4] = v4;
    }
}

// kC: reduce 16 v-partials + 64 asum-partials, subtract a_sum*k_mean, normalize.
__global__ void netvlad_kC(const float* __restrict__ vpart,
                           const float* __restrict__ apart,
                           const float* __restrict__ kmean,
                           float* __restrict__ out) {
    const int bi = blockIdx.x / KK;
    const int k  = blockIdx.x % KK;
    const int t  = threadIdx.x;   // d

    float v = 0.0f;
    for (int j = 0; j < 16; j++)
        v += vpart[(((size_t)bi * 16 + j) * KK + k) * DD + t];

    float asum = 0.0f;
    for (int j = 0; j < 64; j++)
        asum += apart[((size_t)bi * 64 + j) * KK + k];

    v -= asum * kmean[(size_t)k * DD + t];

    float sq = v * v;
    sq += __shfl_xor(sq, 1);  sq += __shfl_xor(sq, 2);  sq += __shfl_xor(sq, 4);
    sq += __shfl_xor(sq, 8);  sq += __shfl_xor(sq, 16); sq += __shfl_xor(sq, 32);
    __shared__ float red[4];
    if ((t & 63) == 0) red[t >> 6] = sq;
    __syncthreads();
    float tot = red[0] + red[1] + red[2] + red[3];

    const float EPS = 1e-12f;
    float invn = 1.0f / fmaxf(sqrtf(tot), EPS);
    const float invK = 0.1767766952966369f;  // 1/sqrt(32): global norm after intra-norm
    out[((size_t)bi * KK + k) * DD + t] = v * invn * invK;
}

extern "C" void kernel_launch(void* const* d_in, const int* in_sizes, int n_in,
                              void* d_out, int out_size, void* d_ws, size_t ws_size,
                              hipStream_t stream) {
    const float* x     = (const float*)d_in[0];
    const float* W     = (const float*)d_in[1];
    const float* bias  = (const float*)d_in[2];
    const float* kmean = (const float*)d_in[3];
    float* out = (float*)d_out;

    // ws carve: vpart (256*32*256 f32 = 8.4MB) | apart (1024*32 f32 = 128KB)
    float* vpart = (float*)d_ws;
    float* apart = vpart + (size_t)256 * KK * DD;

    hipLaunchKernelGGL(netvlad_k1, dim3(256), dim3(256), 0, stream,
                       x, W, bias, vpart, apart);
    hipLaunchKernelGGL(netvlad_kC, dim3(BB * KK), dim3(256), 0, stream,
                       vpart, apart, kmean, out);
}

// Round 22
// 60.064 us; speedup vs baseline: 1.6694x; 1.1294x over previous
//
#include <hip/hip_runtime.h>
#include <hip/hip_bf16.h>
#include <math.h>

#define BB 16
#define NN 16384
#define DD 256
#define KK 32

typedef short bf16x8 __attribute__((ext_vector_type(8)));
typedef float f32x4 __attribute__((ext_vector_type(4)));

__device__ inline unsigned pk2(float lo, float hi) {
    __hip_bfloat162 h = __float22bfloat162_rn(make_float2(lo, hi));
    union { __hip_bfloat162 h; unsigned u; } v; v.h = h;
    return v.u;
}
__device__ inline bf16x8 u4bf(uint4 q) {
    union { uint4 u; bf16x8 v; } c; c.u = q; return c.v;
}

#define UE(v, e) ((e) == 0 ? (v).x : (e) == 1 ? (v).y : (e) == 2 ? (v).z : (v).w)

// r19 (67.8us) with the SECOND global x read (ca col-loads) eliminated:
// E packs pf->xq regs (same pk2s) and ds_writes a wave-private xh row tile
// (r8-validated swizzle); next iter col-reads xh -> xt (r8-validated packing);
// agg defers 2 subs (af rotated through named regs, rule #20). Removes 256MB
// of L2 re-read traffic + its latency exposure; suspected partial L2->HBM
// thrash (live window ~4MB/XCD = capacity). Fence-free (r18); bounds(256,1),
// VGPR ~280 < 512 -> zero spill; LDS 80KB, 1 block/CU (r19 residency).
__launch_bounds__(256, 1)
__global__ void netvlad_k1(const float* __restrict__ x,
                           const float* __restrict__ W,
                           const float* __restrict__ bias,
                           float* __restrict__ vpart,
                           float* __restrict__ apart) {
    __shared__ __align__(16) char lds[81920];
    // [0,16384):     Wl bf16, byte = k*512 + (dbyte ^ ((k&7)<<4))
    // [16384,49152): xh per-wave 8KB row tile: ushort idx = n*256 + (d ^ ((n&7)<<3)) chunked
    // [49152,81920): xt per-wave 8KB: d*32 + (nbyte ^ (((d>>3)&1)<<4))
    // epilogue: vbuf f32 [32][260] at byte 0

    const int t   = threadIdx.x;
    const int l   = t & 63;
    const int w   = t >> 6;
    const int l15 = l & 15;
    const int lg4 = l >> 4;
    const int bid = blockIdx.x;
    const int b   = bid >> 4;            // batch (16 blocks per batch)
    const int blk = bid & 15;            // 1024-row chunk

    // ---- stage Wl (bf16, swizzled) once ----
    for (int i = 0; i < 8; i++) {
        int f = i * 256 + t;             // float4 index in [0,2048)
        int k = f >> 6, c4 = f & 63;
        float4 wv = ((const float4*)W)[f];
        int byte = k * 512 + ((c4 * 8) ^ ((k & 7) << 4));
        *(uint2*)(lds + byte) = make_uint2(pk2(wv.x, wv.y), pk2(wv.z, wv.w));
    }
    const float cb0 = bias[l15];
    const float cb1 = bias[16 + l15];
    __syncthreads();                     // once; Wl read-only afterwards

    char* xhw = lds + 16384 + w * 8192;  // wave-private bf16 row tile
    char* xtw = lds + 49152 + w * 8192;  // wave-private transposed tile

    f32x4 acc0[16], acc1[16];
#pragma unroll
    for (int i = 0; i < 16; i++) { acc0[i] = (f32x4){0,0,0,0}; acc1[i] = (f32x4){0,0,0,0}; }
    float asr0 = 0.f, asr1 = 0.f;

    const float* xbase = x + ((size_t)b * NN + (size_t)blk * 1024) * DD;

    // prologue: prefetch sub-0 row-slices
    float4 pf[16];
    {
        const float* xr = xbase + (size_t)(w * 16 + l15) * DD + lg4 * 8;
#pragma unroll
        for (int ks = 0; ks < 8; ks++) {
            pf[2 * ks]     = *(const float4*)(xr + ks * 32);
            pf[2 * ks + 1] = *(const float4*)(xr + ks * 32 + 4);
        }
    }

    uint4 af0_m1 = make_uint4(0,0,0,0), af1_m1 = make_uint4(0,0,0,0);
    uint4 af0_m2 = make_uint4(0,0,0,0), af1_m2 = make_uint4(0,0,0,0);

#pragma unroll 1
    for (int s = 0; s < 16; s++) {
        // B: deferred aggregation for sub s-2 (xt holds s-2; af_m2 = a(s-2))
        if (s > 1) {
#pragma unroll
            for (int dt = 0; dt < 16; dt++) {
                int d = dt * 16 + l15;
                unsigned sw = ((unsigned)(d >> 3) & 1u) << 4;
                uint2 bl = *(const uint2*)(xtw + d * 32 + ((lg4 * 8) ^ sw));
                bf16x8 bv = u4bf(make_uint4(bl.x, bl.y, 0, 0));
                acc0[dt] = __builtin_amdgcn_mfma_f32_16x16x32_bf16(u4bf(af0_m2), bv, acc0[dt], 0, 0, 0);
                acc1[dt] = __builtin_amdgcn_mfma_f32_16x16x32_bf16(u4bf(af1_m2), bv, acc1[dt], 0, 0, 0);
            }
        }

        // C/D: build xt(s-1) from xh col-reads (xh holds sub s-1 rows).
        // In-order same-wave DS: B's xt reads precede these xt writes.
        if (s > 0) {
#pragma unroll
            for (int half = 0; half < 2; half++) {
                ushort4 cv[8];
#pragma unroll
                for (int i = 0; i < 8; i++) {
                    int r  = half * 8 + i;
                    int us = r * 256 + ((((4 * l) & ~7) ^ ((r & 7) << 3)) | ((4 * l) & 7));
                    cv[i] = *(const ushort4*)(xhw + us * 2);
                }
#pragma unroll
                for (int e = 0; e < 4; e++) {
                    uint4 q;
                    q.x = (unsigned)UE(cv[0], e) | ((unsigned)UE(cv[1], e) << 16);
                    q.y = (unsigned)UE(cv[2], e) | ((unsigned)UE(cv[3], e) << 16);
                    q.z = (unsigned)UE(cv[4], e) | ((unsigned)UE(cv[5], e) << 16);
                    q.w = (unsigned)UE(cv[6], e) | ((unsigned)UE(cv[7], e) << 16);
                    int d = 4 * l + e;
                    unsigned sw = ((unsigned)(d >> 3) & 1u) << 4;
                    *(uint4*)(xtw + d * 32 + (((unsigned)(half * 16)) ^ sw)) = q;
                }
            }
        }

        // E: logits mfma (A = x row-frags packed from pf, B = W^T from Wl)
        f32x4 c0 = (f32x4){cb0, cb0, cb0, cb0};
        f32x4 c1 = (f32x4){cb1, cb1, cb1, cb1};
        uint4 xq[8];
        {
            const unsigned swk = ((unsigned)(l15 & 7)) << 4;
#pragma unroll
            for (int ks = 0; ks < 8; ks++) {
                uint4 q;
                q.x = pk2(pf[2 * ks].x,     pf[2 * ks].y);
                q.y = pk2(pf[2 * ks].z,     pf[2 * ks].w);
                q.z = pk2(pf[2 * ks + 1].x, pf[2 * ks + 1].y);
                q.w = pk2(pf[2 * ks + 1].z, pf[2 * ks + 1].w);
                xq[ks] = q;
                bf16x8 ax = u4bf(q);
                bf16x8 w0 = *(const bf16x8*)(lds + l15 * 512        + (((unsigned)(ks * 64 + lg4 * 16)) ^ swk));
                bf16x8 w1 = *(const bf16x8*)(lds + (16 + l15) * 512 + (((unsigned)(ks * 64 + lg4 * 16)) ^ swk));
                c0 = __builtin_amdgcn_mfma_f32_16x16x32_bf16(ax, w0, c0, 0, 0, 0);
                c1 = __builtin_amdgcn_mfma_f32_16x16x32_bf16(ax, w1, c1, 0, 0, 0);
            }
        }

        // E2: publish xh(s) — lane (l15,lg4) owns row l15, cols ks*32+lg4*8
        //     (r8-validated swizzle; read back at C of sub s+1)
#pragma unroll
        for (int ks = 0; ks < 8; ks++) {
            int us = l15 * 256 + ((ks * 32 + lg4 * 8) ^ ((l15 & 7) << 3));
            *(uint4*)(xhw + us * 2) = xq[ks];
        }

        // F: issue next sub's HBM row-slice prefetch
        if (s < 15) {
            const float* xr = xbase + ((size_t)(s + 1) * 64 + (size_t)(w * 16 + l15)) * DD + lg4 * 8;
#pragma unroll
            for (int ks = 0; ks < 8; ks++) {
                pf[2 * ks]     = *(const float4*)(xr + ks * 32);
                pf[2 * ks + 1] = *(const float4*)(xr + ks * 32 + 4);
            }
        }

        // G: softmax over k=32 (16 lanes x 2 tiles), fully in-register
        float a0v[4], a1v[4];
#pragma unroll
        for (int r = 0; r < 4; r++) {
            float m = fmaxf(c0[r], c1[r]);
            m = fmaxf(m, __shfl_xor(m, 1));
            m = fmaxf(m, __shfl_xor(m, 2));
            m = fmaxf(m, __shfl_xor(m, 4));
            m = fmaxf(m, __shfl_xor(m, 8));
            float p0 = __expf(c0[r] - m), p1 = __expf(c1[r] - m);
            float ss = p0 + p1;
            ss += __shfl_xor(ss, 1);
            ss += __shfl_xor(ss, 2);
            ss += __shfl_xor(ss, 4);
            ss += __shfl_xor(ss, 8);
            float inv = 1.0f / ss;
            a0v[r] = p0 * inv; a1v[r] = p1 * inv;
        }
        asr0 += a0v[0] + a0v[1] + a0v[2] + a0v[3];
        asr1 += a1v[0] + a1v[1] + a1v[2] + a1v[3];
        // rotate deferred a-fragments (named regs, rule #20)
        af0_m2 = af0_m1;  af1_m2 = af1_m1;
        af0_m1 = make_uint4(pk2(a0v[0], a0v[1]), pk2(a0v[2], a0v[3]), 0, 0);
        af1_m1 = make_uint4(pk2(a1v[0], a1v[1]), pk2(a1v[2], a1v[3]), 0, 0);
    }

    // ---- tail 1: aggregate sub 14 (xt holds sub 14; af_m2 = a(14)) ----
#pragma unroll
    for (int dt = 0; dt < 16; dt++) {
        int d = dt * 16 + l15;
        unsigned sw = ((unsigned)(d >> 3) & 1u) << 4;
        uint2 bl = *(const uint2*)(xtw + d * 32 + ((lg4 * 8) ^ sw));
        bf16x8 bv = u4bf(make_uint4(bl.x, bl.y, 0, 0));
        acc0[dt] = __builtin_amdgcn_mfma_f32_16x16x32_bf16(u4bf(af0_m2), bv, acc0[dt], 0, 0, 0);
        acc1[dt] = __builtin_amdgcn_mfma_f32_16x16x32_bf16(u4bf(af1_m2), bv, acc1[dt], 0, 0, 0);
    }
    // ---- tail 2: build xt(15) from xh, aggregate sub 15 (af_m1 = a(15)) ----
#pragma unroll
    for (int half = 0; half < 2; half++) {
        ushort4 cv[8];
#pragma unroll
        for (int i = 0; i < 8; i++) {
            int r  = half * 8 + i;
            int us = r * 256 + ((((4 * l) & ~7) ^ ((r & 7) << 3)) | ((4 * l) & 7));
            cv[i] = *(const ushort4*)(xhw + us * 2);
        }
#pragma unroll
        for (int e = 0; e < 4; e++) {
            uint4 q;
            q.x = (unsigned)UE(cv[0], e) | ((unsigned)UE(cv[1], e) << 16);
            q.y = (unsigned)UE(cv[2], e) | ((unsigned)UE(cv[3], e) << 16);
            q.z = (unsigned)UE(cv[4], e) | ((unsigned)UE(cv[5], e) << 16);
            q.w = (unsigned)UE(cv[6], e) | ((unsigned)UE(cv[7], e) << 16);
            int d = 4 * l + e;
            unsigned sw = ((unsigned)(d >> 3) & 1u) << 4;
            *(uint4*)(xtw + d * 32 + (((unsigned)(half * 16)) ^ sw)) = q;
        }
    }
#pragma unroll
    for (int dt = 0; dt < 16; dt++) {
        int d = dt * 16 + l15;
        unsigned sw = ((unsigned)(d >> 3) & 1u) << 4;
        uint2 bl = *(const uint2*)(xtw + d * 32 + ((lg4 * 8) ^ sw));
        bf16x8 bv = u4bf(make_uint4(bl.x, bl.y, 0, 0));
        acc0[dt] = __builtin_amdgcn_mfma_f32_16x16x32_bf16(u4bf(af0_m1), bv, acc0[dt], 0, 0, 0);
        acc1[dt] = __builtin_amdgcn_mfma_f32_16x16x32_bf16(u4bf(af1_m1), bv, acc1[dt], 0, 0, 0);
    }

    // ---- asum: reduce over lg4 groups; per-wave global partials ----
    asr0 += __shfl_xor(asr0, 16);  asr0 += __shfl_xor(asr0, 32);
    asr1 += __shfl_xor(asr1, 16);  asr1 += __shfl_xor(asr1, 32);
    if (l < 16) {
        float* ap = apart + ((size_t)bid * 4 + w) * KK;
        ap[l15]      = asr0;
        ap[16 + l15] = asr1;
    }

    // ---- epilogue: cross-wave v reduce via LDS (Wl/xh/xt dead) ----
    __syncthreads();
    float* vb = (float*)lds;             // [32][260] f32
    if (w == 0) {
#pragma unroll
        for (int dt = 0; dt < 16; dt++) {
            int d = dt * 16 + l15;
#pragma unroll
            for (int r = 0; r < 4; r++) {
                int k0 = lg4 * 4 + r;
                vb[k0 * 260 + d]        = acc0[dt][r];
                vb[(16 + k0) * 260 + d] = acc1[dt][r];
            }
        }
    }
    __syncthreads();
    if (w == 1) {
#pragma unroll
        for (int dt = 0; dt < 16; dt++) {
            int d = dt * 16 + l15;
#pragma unroll
            for (int r = 0; r < 4; r++) {
                int k0 = lg4 * 4 + r;
                vb[k0 * 260 + d]        += acc0[dt][r];
                vb[(16 + k0) * 260 + d] += acc1[dt][r];
            }
        }
    }
    __syncthreads();
    if (w == 2) {
#pragma unroll
        for (int dt = 0; dt < 16; dt++) {
            int d = dt * 16 + l15;
#pragma unroll
            for (int r = 0; r < 4; r++) {
                int k0 = lg4 * 4 + r;
                vb[k0 * 260 + d]        += acc0[dt][r];
                vb[(16 + k0) * 260 + d] += acc1[dt][r];
            }
        }
    }
    __syncthreads();
    if (w == 3) {
#pragma unroll
        for (int dt = 0; dt < 16; dt++) {
            int d = dt * 16 + l15;
#pragma unroll
            for (int r = 0; r < 4; r++) {
                int k0 = lg4 * 4 + r;
                vb[k0 * 260 + d]        += acc0[dt][r];
                vb[(16 + k0) * 260 + d] += acc1[dt][r];
            }
        }
    }
    __syncthreads();
    float* vp = vpart + (size_t)bid * KK * DD;
#pragma unroll
    for (int i = 0; i < 8; i++) {
        int f = i * 256 + t;
        int k = f >> 6, c4 = f & 63;
        f32x4 v4 = *(const f32x4*)&vb[k * 260 + c4 * 4];
        *(f32x4*)&vp[(size_t)k * DD + c4 * 4] = v4;
    }
}

// kC: reduce 16 v-partials + 64 asum-partials, subtract a_sum*k_mean, normalize.
__global__ void netvlad_kC(const float* __restrict__ vpart,
                           const float* __restrict__ apart,
                           const float* __restrict__ kmean,
                           float* __restrict__ out) {
    const int bi = blockIdx.x / KK;
    const int k  = blockIdx.x % KK;
    const int t  = threadIdx.x;   // d

    float v = 0.0f;
    for (int j = 0; j < 16; j++)
        v += vpart[(((size_t)bi * 16 + j) * KK + k) * DD + t];

    float asum = 0.0f;
    for (int j = 0; j < 64; j++)
        asum += apart[((size_t)bi * 64 + j) * KK + k];

    v -= asum * kmean[(size_t)k * DD + t];

    float sq = v * v;
    sq += __shfl_xor(sq, 1);  sq += __shfl_xor(sq, 2);  sq += __shfl_xor(sq, 4);
    sq += __shfl_xor(sq, 8);  sq += __shfl_xor(sq, 16); sq += __shfl_xor(sq, 32);
    __shared__ float red[4];
    if ((t & 63) == 0) red[t >> 6] = sq;
    __syncthreads();
    float tot = red[0] + red[1] + red[2] + red[3];

    const float EPS = 1e-12f;
    float invn = 1.0f / fmaxf(sqrtf(tot), EPS);
    const float invK = 0.1767766952966369f;  // 1/sqrt(32): global norm after intra-norm
    out[((size_t)bi * KK + k) * DD + t] = v * invn * invK;
}

extern "C" void kernel_launch(void* const* d_in, const int* in_sizes, int n_in,
                              void* d_out, int out_size, void* d_ws, size_t ws_size,
                              hipStream_t stream) {
    const float* x     = (const float*)d_in[0];
    const float* W     = (const float*)d_in[1];
    const float* bias  = (const float*)d_in[2];
    const float* kmean = (const float*)d_in[3];
    float* out = (float*)d_out;

    // ws carve: vpart (256*32*256 f32 = 8.4MB) | apart (1024*32 f32 = 128KB)
    float* vpart = (float*)d_ws;
    float* apart = vpart + (size_t)256 * KK * DD;

    hipLaunchKernelGGL(netvlad_k1, dim3(256), dim3(256), 0, stream,
                       x, W, bias, vpart, apart);
    hipLaunchKernelGGL(netvlad_kC, dim3(BB * KK), dim3(256), 0, stream,
                       vpart, apart, kmean, out);
}